// Round 8
// baseline (250.512 us; speedup 1.0000x reference)
//
#include <hip/hip_runtime.h>
#include <cstddef>
#include <cstdint>

// DigitCaps dynamic routing — round 8: u REGISTER-RESIDENT.
// Round-7 post-mortem: latency-bound, not VALU-bound (VALUBusy fell 68->59
// with dur unchanged). Structural fix: compute u ONCE (pass 0) and keep it
// in registers; routing passes 1-2 touch no memory for u and no dot8s.
//  - BQ=1, NTH=1024, grid=512 (one batch item per block)
//  - per-lane u slice: 10 o x 18 k f16 = 90 packed VGPRs (fits <=128 budget
//    at 16 waves/CU); o-pairs packed so one shfl-reduce serves two o's
//  - W streamed once per block: L2 W traffic 2.26 GB -> 1.5 GB total
// B=512, O=10, I=1152, OW=16, S=8, ITER=3.
//   pass0: u = W.x (capture in regs); s1 = 0.1*sum_i u ; v1
//   pass1: b = u.v1      -> softmax -> s2 ; v2      (register-only)
//   pass2: b = u.(v1+v2) -> softmax -> s3 ; out     (register-only)

typedef _Float16 h2 __attribute__((ext_vector_type(2)));
typedef __fp16 fp16v2 __attribute__((ext_vector_type(2)));  // cvt_pkrtz ret type

constexpr int O_ = 10, I_ = 1152, W_ = 16, S_ = 8;
constexpr int NTH = 1024, NWV = 16;
constexpr int SLOTS = NWV * 4;      // 64 concurrent i (16 lanes per i)
constexpr int KSEQ = I_ / SLOTS;    // 18 sequential i per lane
constexpr int OQ = O_ / 2;          // 5 packed o-pairs
constexpr int WROW = O_ * W_ * S_;  // 1280 halves per i in transposed W

union U32H2 { uint32_t u; h2 h; fp16v2 f; };
__device__ __forceinline__ h2 as_h2(uint32_t u) { U32H2 c; c.u = u; return c.h; }
__device__ __forceinline__ uint32_t as_u32(h2 h) { U32H2 c; c.h = h; return c.u; }
__device__ __forceinline__ h2 cvt_pk(float a, float b) {
  U32H2 c; c.f = __builtin_amdgcn_cvt_pkrtz(a, b); return c.h;
}

// W prep: fp32 [o][i][w][s] -> f16 [i][o][w][s]  (2,949,120 B into d_ws)
constexpr int W4TOT = O_ * I_ * W_ * S_ / 4;  // 368640 float4s
__global__ __launch_bounds__(256) void wprep(const float4* __restrict__ Wg,
                                             uint2* __restrict__ Wt) {
  int idx = blockIdx.x * 256 + threadIdx.x;
  if (idx >= W4TOT) return;
  int w2 = idx & 31;
  int oi = idx >> 5;        // o*I_ + i
  int o = oi / I_;
  int i = oi - o * I_;
  float4 v = Wg[idx];
  uint2 pk;
  pk.x = as_u32(cvt_pk(v.x, v.y));
  pk.y = as_u32(cvt_pk(v.z, v.w));
  Wt[(i * O_ + o) * 32 + w2] = pk;
}

__device__ __forceinline__ float dot8(const uint4& wv, const uint32_t* xr) {
  return __builtin_amdgcn_fdot2(as_h2(wv.x), as_h2(xr[0]),
          __builtin_amdgcn_fdot2(as_h2(wv.y), as_h2(xr[1]),
           __builtin_amdgcn_fdot2(as_h2(wv.z), as_h2(xr[2]),
            __builtin_amdgcn_fdot2(as_h2(wv.w), as_h2(xr[3]),
                                   0.f, false), false), false), false);
}

__global__ __launch_bounds__(NTH, 1) void digitcaps_fused(
    const float* __restrict__ xg, const _Float16* __restrict__ Wt,
    float* __restrict__ out) {
  __shared__ _Float16 xl[I_ * S_];          // 18,432 B (f16 x, one batch item)
  __shared__ float s_buf[NWV][O_][W_];      // 10,240 B
  __shared__ float vcur[O_ * W_];           // v1, then v1+v2
  __shared__ float v1s[O_ * W_];

  const int tid = threadIdx.x, blk = blockIdx.x;
  const int wave = tid >> 6, lane = tid & 63;
  const int wg = lane & 15;     // w column 0..15
  const int isub = lane >> 4;   // 0..3
  const int ib = wave * 4 + isub;  // i-slot; i = ib + 64*k

  // ---- stage x -> f16 LDS ----
  {
    const float4* xb = (const float4*)(xg + (size_t)blk * (I_ * S_));
    uint2* xw = (uint2*)xl;
#pragma unroll
    for (int j = 0; j < 3; ++j) {
      int f = j * NTH + tid;            // 2304 float4s total
      if (f < I_ * S_ / 4) {
        float4 v = xb[f];
        uint2 pk;
        pk.x = as_u32(cvt_pk(v.x, v.y));
        pk.y = as_u32(cvt_pk(v.z, v.w));
        xw[f] = pk;
      }
    }
  }
  __syncthreads();

  h2 u[OQ][KSEQ];   // the register-resident u slice: 90 packed VGPRs

  // ================= pass 0 : compute u, s1 = 0.1 * sum_i u ================
  {
    float S0[O_];
#pragma unroll
    for (int o = 0; o < O_; ++o) S0[o] = 0.f;

#pragma unroll
    for (int k = 0; k < KSEQ; ++k) {
      const int i = ib + SLOTS * k;
      uint32_t xr[4];
      {
        uint4 t = *(const uint4*)&xl[i * S_];
        xr[0] = t.x; xr[1] = t.y; xr[2] = t.z; xr[3] = t.w;
      }
      const _Float16* wi = Wt + (size_t)i * WROW + wg * S_;
#pragma unroll
      for (int oq = 0; oq < OQ; ++oq) {
        uint4 wv0 = *(const uint4*)(wi + (2 * oq) * (W_ * S_));
        uint4 wv1 = *(const uint4*)(wi + (2 * oq + 1) * (W_ * S_));
        float f0 = dot8(wv0, xr);
        float f1 = dot8(wv1, xr);
        u[oq][k] = cvt_pk(f0, f1);
        S0[2 * oq] += f0;
        S0[2 * oq + 1] += f1;
      }
    }
#pragma unroll
    for (int o = 0; o < O_; ++o) {
      float s = S0[o];
      s += __shfl_xor(s, 16);
      s += __shfl_xor(s, 32);
      S0[o] = s;
    }
    if (isub == 0) {
#pragma unroll
      for (int o = 0; o < O_; ++o) s_buf[wave][o][wg] = S0[o];
    }
    __syncthreads();

    if (tid < O_ * W_) {
      const int r = tid;
      float s = 0.f;
#pragma unroll
      for (int wv = 0; wv < NWV; ++wv) s += s_buf[wv][r >> 4][r & 15];
      s *= 0.1f;
      float n2 = s * s;
      n2 += __shfl_xor(n2, 1);
      n2 += __shfl_xor(n2, 2);
      n2 += __shfl_xor(n2, 4);
      n2 += __shfl_xor(n2, 8);
      const float v = s * sqrtf(n2) / (1.0f + n2);
      vcur[r] = v;
      v1s[r] = v;
    }
    __syncthreads();
  }

  // ============== passes 1,2 : register-only routing =======================
  for (int pass = 1; pass < 3; ++pass) {
    h2 vrpk[OQ];   // packed o-pair v slice for this lane's w column
#pragma unroll
    for (int oq = 0; oq < OQ; ++oq)
      vrpk[oq] = cvt_pk(vcur[(2 * oq) * W_ + wg], vcur[(2 * oq + 1) * W_ + wg]);

    float S[O_];
#pragma unroll
    for (int o = 0; o < O_; ++o) S[o] = 0.f;

#pragma unroll
    for (int k = 0; k < KSEQ; ++k) {
      // logits: p[o] = sum_w u*v ; packed pair per reduce
      h2 ppk[OQ];
#pragma unroll
      for (int oq = 0; oq < OQ; ++oq) ppk[oq] = u[oq][k] * vrpk[oq];
#pragma unroll
      for (int oq = 0; oq < OQ; ++oq) {
#pragma unroll
        for (int d = 1; d <= 8; d <<= 1)
          ppk[oq] = ppk[oq] + as_h2((uint32_t)__shfl_xor((int)as_u32(ppk[oq]), d));
      }
      // softmax over the 10 o (f32, no max-sub: logits bounded)
      float e[O_];
      float es = 0.f;
#pragma unroll
      for (int oq = 0; oq < OQ; ++oq) {
        e[2 * oq]     = __expf((float)ppk[oq][0]);
        e[2 * oq + 1] = __expf((float)ppk[oq][1]);
        es += e[2 * oq] + e[2 * oq + 1];
      }
      const float inv = 1.0f / es;
#pragma unroll
      for (int oq = 0; oq < OQ; ++oq) {
        S[2 * oq]     += (e[2 * oq] * inv)     * (float)u[oq][k][0];
        S[2 * oq + 1] += (e[2 * oq + 1] * inv) * (float)u[oq][k][1];
      }
    }

    // reduce s over the 4 i-sub lane groups (bits 4,5)
#pragma unroll
    for (int o = 0; o < O_; ++o) {
      float s = S[o];
      s += __shfl_xor(s, 16);
      s += __shfl_xor(s, 32);
      S[o] = s;
    }
    if (isub == 0) {
#pragma unroll
      for (int o = 0; o < O_; ++o) s_buf[wave][o][wg] = S[o];
    }
    __syncthreads();

    // cross-wave reduce + squash on 160 threads
    if (tid < O_ * W_) {
      const int r = tid;
      float s = 0.f;
#pragma unroll
      for (int wv = 0; wv < NWV; ++wv) s += s_buf[wv][r >> 4][r & 15];
      float n2 = s * s;
      n2 += __shfl_xor(n2, 1);
      n2 += __shfl_xor(n2, 2);
      n2 += __shfl_xor(n2, 4);
      n2 += __shfl_xor(n2, 8);
      const float v = s * sqrtf(n2) / (1.0f + n2);
      if (pass == 1)  vcur[r] = v1s[r] + v;   // v1+v2 for pass 2
      else            out[(size_t)blk * (O_ * W_) + r] = v;
    }
    __syncthreads();
  }
}

extern "C" void kernel_launch(void* const* d_in, const int* in_sizes, int n_in,
                              void* d_out, int out_size, void* d_ws, size_t ws_size,
                              hipStream_t stream) {
  const float* x = (const float*)d_in[0];   // [512, 1152, 8]
  const float* W = (const float*)d_in[1];   // [1, 10, 1152, 16, 8]
  float* out = (float*)d_out;               // [512, 10, 16]
  _Float16* Wt = (_Float16*)d_ws;           // 2,949,120 B f16 transposed W

  hipLaunchKernelGGL(wprep, dim3((W4TOT + 255) / 256), dim3(256), 0, stream,
                     (const float4*)W, (uint2*)Wt);
  hipLaunchKernelGGL(digitcaps_fused, dim3(512), dim3(NTH), 0, stream,
                     x, Wt, out);
}

// Round 9
// 183.873 us; speedup vs baseline: 1.3624x; 1.3624x over previous
//
#include <hip/hip_runtime.h>
#include <cstddef>
#include <cstdint>

// DigitCaps dynamic routing — round 9: i-SPLIT ACROSS 2 BLOCKS/CU.
// Round-8 post-mortem: u-in-registers spills (16-wave blocks cap VGPR at 128,
// compiler chose 64; u=90 regs can't fit) — reverted. Round-5/7 model: the
// W-sweep is Little's-law limited (~23.6 B/cyc/CU L2 pull at 16 waves/CU).
// Fix: 32 waves/CU via 2 blocks/CU, WITHOUT doubling W traffic: each block
// sweeps only HALF the i-range (half of W) per pass. Cross-block s-reduction
// via tiny combine kernels between sweeps (kernel boundary = sync, no
// cooperative launch needed).
//   wprep -> sweep<0> -> combine<0> -> sweep<1> -> combine<1> -> sweep<2> -> combine<2>
// B=512, O=10, I=1152, OW=16, S=8, ITER=3.
//   pass0: s1 = 0.1*sum_i u ; v1
//   pass1: b = u.v1      -> softmax -> s2 ; v2
//   pass2: b = u.(v1+v2) -> softmax -> s3 ; out
// u recomputed per sweep from f16 W (transposed [i][o][w][s] in d_ws,
// L2-resident) and f16 x (staged in LDS per sweep).

typedef _Float16 h2 __attribute__((ext_vector_type(2)));
typedef __fp16 fp16v2 __attribute__((ext_vector_type(2)));  // cvt_pkrtz ret type

constexpr int O_ = 10, I_ = 1152, W_ = 16, S_ = 8;
constexpr int BQ = 2;               // batch items per block
constexpr int NTH = 1024, NWV = 16;
constexpr int IH = I_ / 2;          // 576: i per block (half range)
constexpr int SLOTS = NWV * 4;      // 64 concurrent i (16 lanes per i)
constexpr int KSEQ = IH / SLOTS;    // 9 sequential i per lane per sweep
constexpr int WROW = O_ * W_ * S_;  // 1280 halves per i in transposed W
constexpr int NBP = 256;            // batch pairs
constexpr int OW = O_ * W_;         // 160

union U32H2 { uint32_t u; h2 h; fp16v2 f; };
__device__ __forceinline__ h2 as_h2(uint32_t u) { U32H2 c; c.u = u; return c.h; }
__device__ __forceinline__ uint32_t as_u32(h2 h) { U32H2 c; c.h = h; return c.u; }
__device__ __forceinline__ h2 cvt_pk(float a, float b) {
  U32H2 c; c.f = __builtin_amdgcn_cvt_pkrtz(a, b); return c.h;
}

// W prep: fp32 [o][i][w][s] -> f16 [i][o][w][s]  (2,949,120 B into d_ws)
constexpr int W4TOT = O_ * I_ * W_ * S_ / 4;  // 368640 float4s
__global__ __launch_bounds__(256) void wprep(const float4* __restrict__ Wg,
                                             uint2* __restrict__ Wt) {
  int idx = blockIdx.x * 256 + threadIdx.x;
  if (idx >= W4TOT) return;
  int w2 = idx & 31;
  int oi = idx >> 5;        // o*I_ + i
  int o = oi / I_;
  int i = oi - o * I_;
  float4 v = Wg[idx];
  uint2 pk;
  pk.x = as_u32(cvt_pk(v.x, v.y));
  pk.y = as_u32(cvt_pk(v.z, v.w));
  Wt[(i * O_ + o) * 32 + w2] = pk;
}

__device__ __forceinline__ float dot8(const uint4& wv, const uint32_t* xr) {
  return __builtin_amdgcn_fdot2(as_h2(wv.x), as_h2(xr[0]),
          __builtin_amdgcn_fdot2(as_h2(wv.y), as_h2(xr[1]),
           __builtin_amdgcn_fdot2(as_h2(wv.z), as_h2(xr[2]),
            __builtin_amdgcn_fdot2(as_h2(wv.w), as_h2(xr[3]),
                                   0.f, false), false), false), false);
}

// Sweep: 512 blocks; block = (batch-pair bp, i-half h). Computes the partial
// s over its 576 i's and writes P[(bp*2+h)][bb][r]. PASS>0 reads Vcur.
template <int PASS>
__global__ __launch_bounds__(NTH, 8) void sweep(
    const float* __restrict__ xg, const _Float16* __restrict__ Wt,
    const float* __restrict__ Vcur, float* __restrict__ P) {
  __shared__ _Float16 xl[BQ * IH * S_];      // 18,432 B
  __shared__ float s_buf[NWV][BQ][O_][W_];   // 20,480 B

  const int tid = threadIdx.x, blk = blockIdx.x;
  const int bp = blk >> 1, h = blk & 1, b0 = bp * BQ;
  const int wave = tid >> 6, lane = tid & 63;
  const int wg = lane & 15;     // w column 0..15
  const int isub = lane >> 4;   // 0..3
  const int ib = wave * 4 + isub;  // local i-slot; il = ib + 64*k

  // ---- stage this block's x slice -> f16 LDS ----
  {
    const float4* xb = (const float4*)xg;
    uint2* xw = (uint2*)xl;
#pragma unroll
    for (int j = 0; j < 3; ++j) {
      int f = j * NTH + tid;                 // 2304 float4s total
      if (f < BQ * IH * S_ / 4) {
        int b = f / (IH * S_ / 4);           // 0..1
        int rem = f - b * (IH * S_ / 4);
        float4 v = xb[(size_t)(b0 + b) * (I_ * S_ / 4) + h * (IH * S_ / 4) + rem];
        uint2 pk;
        pk.x = as_u32(cvt_pk(v.x, v.y));
        pk.y = as_u32(cvt_pk(v.z, v.w));
        xw[f] = pk;
      }
    }
  }
  __syncthreads();

  if (PASS == 0) {
    float S[BQ][O_];
#pragma unroll
    for (int b = 0; b < BQ; ++b)
#pragma unroll
      for (int o = 0; o < O_; ++o) S[b][o] = 0.f;

#pragma unroll 2
    for (int k = 0; k < KSEQ; ++k) {
      const int il = ib + SLOTS * k;
      const int gi = h * IH + il;
      uint32_t xr[BQ][4];
#pragma unroll
      for (int b = 0; b < BQ; ++b) {
        uint4 t = *(const uint4*)&xl[(b * IH + il) * S_];
        xr[b][0] = t.x; xr[b][1] = t.y; xr[b][2] = t.z; xr[b][3] = t.w;
      }
      const _Float16* wi = Wt + (size_t)gi * WROW + wg * S_;
#pragma unroll
      for (int o = 0; o < O_; ++o) {
        uint4 wv = *(const uint4*)(wi + o * (W_ * S_));
#pragma unroll
        for (int b = 0; b < BQ; ++b) S[b][o] += dot8(wv, xr[b]);
      }
    }
#pragma unroll
    for (int b = 0; b < BQ; ++b)
#pragma unroll
      for (int o = 0; o < O_; ++o) {
        float s = S[b][o];
        s += __shfl_xor(s, 16);
        s += __shfl_xor(s, 32);
        S[b][o] = s;
      }
    if (isub == 0) {
#pragma unroll
      for (int b = 0; b < BQ; ++b)
#pragma unroll
        for (int o = 0; o < O_; ++o) s_buf[wave][b][o][wg] = S[b][o];
    }
  } else {
    // packed batch-pair routing (round-7 inner loop, KSEQ=9)
    h2 vrpk[O_];
#pragma unroll
    for (int o = 0; o < O_; ++o)
      vrpk[o] = cvt_pk(Vcur[(size_t)(b0 + 0) * OW + o * W_ + wg],
                       Vcur[(size_t)(b0 + 1) * OW + o * W_ + wg]);
    h2 Spk[O_];
#pragma unroll
    for (int o = 0; o < O_; ++o) Spk[o] = h2{(_Float16)0, (_Float16)0};

#pragma unroll 2
    for (int k = 0; k < KSEQ; ++k) {
      const int il = ib + SLOTS * k;
      const int gi = h * IH + il;
      uint32_t xr[BQ][4];
#pragma unroll
      for (int b = 0; b < BQ; ++b) {
        uint4 t = *(const uint4*)&xl[(b * IH + il) * S_];
        xr[b][0] = t.x; xr[b][1] = t.y; xr[b][2] = t.z; xr[b][3] = t.w;
      }
      const _Float16* wi = Wt + (size_t)gi * WROW + wg * S_;
      h2 upk[O_], ppk[O_];
#pragma unroll
      for (int o = 0; o < O_; ++o) {
        uint4 wv = *(const uint4*)(wi + o * (W_ * S_));
        float u0 = dot8(wv, xr[0]);
        float u1 = dot8(wv, xr[1]);
        upk[o] = cvt_pk(u0, u1);
        ppk[o] = upk[o] * vrpk[o];
      }
#pragma unroll
      for (int o = 0; o < O_; ++o) {
#pragma unroll
        for (int d = 1; d <= 8; d <<= 1)
          ppk[o] = ppk[o] + as_h2((uint32_t)__shfl_xor((int)as_u32(ppk[o]), d));
      }
      float e0[O_], e1[O_];
      float es0 = 0.f, es1 = 0.f;
#pragma unroll
      for (int o = 0; o < O_; ++o) {
        e0[o] = __expf((float)ppk[o][0]); es0 += e0[o];
        e1[o] = __expf((float)ppk[o][1]); es1 += e1[o];
      }
      const float inv0 = 1.0f / es0, inv1 = 1.0f / es1;
#pragma unroll
      for (int o = 0; o < O_; ++o) {
        h2 c = cvt_pk(e0[o] * inv0, e1[o] * inv1);
        Spk[o] = Spk[o] + c * upk[o];
      }
    }
#pragma unroll
    for (int o = 0; o < O_; ++o) {
      Spk[o] = Spk[o] + as_h2((uint32_t)__shfl_xor((int)as_u32(Spk[o]), 16));
      Spk[o] = Spk[o] + as_h2((uint32_t)__shfl_xor((int)as_u32(Spk[o]), 32));
    }
    if (isub == 0) {
#pragma unroll
      for (int o = 0; o < O_; ++o) {
        s_buf[wave][0][o][wg] = (float)Spk[o][0];
        s_buf[wave][1][o][wg] = (float)Spk[o][1];
      }
    }
  }
  __syncthreads();

  // block partial (sum over 16 waves) -> global P
  if (tid < BQ * OW) {
    const int bb = tid / OW;
    const int r = tid % OW;
    float s = 0.f;
#pragma unroll
    for (int wv = 0; wv < NWV; ++wv) s += s_buf[wv][bb][r >> 4][r & 15];
    P[((size_t)(bp * 2 + h) * BQ + bb) * OW + r] = s;
  }
}

// Combine: 256 blocks x 320 threads. Sum the two i-half partials, squash,
// update Vcur / V1 / out.
template <int PASS>
__global__ __launch_bounds__(320) void combine(
    const float* __restrict__ P, float* __restrict__ Vcur,
    float* __restrict__ V1, float* __restrict__ out) {
  const int bp = blockIdx.x, tid = threadIdx.x;   // tid < 320
  const int bb = tid / OW, r = tid % OW;
  float s = P[((size_t)(bp * 2 + 0) * BQ + bb) * OW + r]
          + P[((size_t)(bp * 2 + 1) * BQ + bb) * OW + r];
  if (PASS == 0) s *= 0.1f;
  float n2 = s * s;
  n2 += __shfl_xor(n2, 1);
  n2 += __shfl_xor(n2, 2);
  n2 += __shfl_xor(n2, 4);
  n2 += __shfl_xor(n2, 8);
  const float v = s * sqrtf(n2) / (1.0f + n2);  // == (n2/(1+n2))*s/sqrt(n2)
  const size_t gi = (size_t)(bp * BQ + bb) * OW + r;
  if (PASS == 0)      { Vcur[gi] = v; V1[gi] = v; }
  else if (PASS == 1) { Vcur[gi] = V1[gi] + v; }   // v1+v2 for pass 2
  else                { out[gi] = v; }
}

extern "C" void kernel_launch(void* const* d_in, const int* in_sizes, int n_in,
                              void* d_out, int out_size, void* d_ws, size_t ws_size,
                              hipStream_t stream) {
  const float* x = (const float*)d_in[0];   // [512, 1152, 8]
  const float* W = (const float*)d_in[1];   // [1, 10, 1152, 16, 8]
  float* out = (float*)d_out;               // [512, 10, 16]

  // ws layout: Wt (2,949,120 B) | P (655,360 B) | Vcur (327,680 B) | V1 (327,680 B)
  _Float16* Wt = (_Float16*)d_ws;
  float* P  = (float*)((char*)d_ws + 2949120);
  float* Vc = (float*)((char*)d_ws + 2949120 + 655360);
  float* V1 = (float*)((char*)d_ws + 2949120 + 655360 + 327680);

  hipLaunchKernelGGL(wprep, dim3((W4TOT + 255) / 256), dim3(256), 0, stream,
                     (const float4*)W, (uint2*)Wt);
  sweep<0><<<dim3(2 * NBP), dim3(NTH), 0, stream>>>(x, Wt, Vc, P);
  combine<0><<<dim3(NBP), dim3(320), 0, stream>>>(P, Vc, V1, out);
  sweep<1><<<dim3(2 * NBP), dim3(NTH), 0, stream>>>(x, Wt, Vc, P);
  combine<1><<<dim3(NBP), dim3(320), 0, stream>>>(P, Vc, V1, out);
  sweep<2><<<dim3(2 * NBP), dim3(NTH), 0, stream>>>(x, Wt, Vc, P);
  combine<2><<<dim3(NBP), dim3(320), 0, stream>>>(P, Vc, V1, out);
}